// Round 1
// baseline (10.333 us; speedup 1.0000x reference)
//
#include <hip/hip_runtime.h>

// Quanvolution collapses analytically:
//   z_i = cos(params[i]) * cos(theta_i)   (theta = 2x2 patch values, row-major)
//   out = [z1*z2*z3, z0*z1, z0*z1*z2, z0*z1*z2*z3]
// Derivation: product state => probs factorize; CNOT ring is a bit permutation
// final bits = (b1^b2^b3, b0^b1, b0^b1^b2, b0^b1^b2^b3); E[(-1)^xor] = prod z_i.

__global__ __launch_bounds__(256) void quanv_kernel(
    const float* __restrict__ x,      // [B,1,28,28]
    const float* __restrict__ params, // [4]
    float* __restrict__ out,          // [B,196*4]
    int N)                            // B*196 patches
{
    int idx = blockIdx.x * blockDim.x + threadIdx.x;
    if (idx >= N) return;

    int b     = idx / 196;
    int patch = idx - b * 196;
    int pr    = patch / 14;
    int pc    = patch - pr * 14;

    const float* base = x + b * 784 + (2 * pr) * 28 + 2 * pc;
    float2 r0 = *reinterpret_cast<const float2*>(base);       // theta0, theta1
    float2 r1 = *reinterpret_cast<const float2*>(base + 28);  // theta2, theta3

    // params pointer is uniform; these fold to scalar loads + uniform cos.
    float cp0 = __cosf(params[0]);
    float cp1 = __cosf(params[1]);
    float cp2 = __cosf(params[2]);
    float cp3 = __cosf(params[3]);

    float z0 = cp0 * __cosf(r0.x);
    float z1 = cp1 * __cosf(r0.y);
    float z2 = cp2 * __cosf(r1.x);
    float z3 = cp3 * __cosf(r1.y);

    float4 o;
    o.y = z0 * z1;        // <Z1>
    o.x = z1 * z2 * z3;   // <Z0>
    o.z = o.y * z2;       // <Z2>
    o.w = o.z * z3;       // <Z3>
    *reinterpret_cast<float4*>(out + (size_t)idx * 4) = o;
}

extern "C" void kernel_launch(void* const* d_in, const int* in_sizes, int n_in,
                              void* d_out, int out_size, void* d_ws, size_t ws_size,
                              hipStream_t stream) {
    const float* x      = (const float*)d_in[0];
    const float* params = (const float*)d_in[1];
    float* out          = (float*)d_out;

    int B = in_sizes[0] / 784;   // 4096
    int N = B * 196;             // patches
    int block = 256;
    int grid  = (N + block - 1) / block;
    quanv_kernel<<<grid, block, 0, stream>>>(x, params, out, N);
}